// Round 1
// baseline (1603.620 us; speedup 1.0000x reference)
//
#include <hip/hip_runtime.h>
#include <math.h>

// Problem constants
#define BATCH 4
#define SEQ   2048
#define EMB   1024
#define DK    1024
#define DV    1024

// GEMM tile params
#define BM 128
#define BN 128
#define BK 16
#define LDT 132   // padded LDS row stride (floats): 16B-aligned rows, 2-way max bank alias

// ---------------------------------------------------------------------------
// NN GEMM: C[m,n] = alpha * sum_k A[m,k]*B[k,n] (+ bias[n])
// A row-major lda=K, B row-major ldb=N. Batched via blockIdx.z with strides.
// ---------------------------------------------------------------------------
__global__ __launch_bounds__(256)
void gemm_nn(const float* __restrict__ A, const float* __restrict__ B,
             const float* __restrict__ bias, float* __restrict__ C,
             int M, int N, int Kd, float alpha,
             size_t sA, size_t sB, size_t sC)
{
    A += (size_t)blockIdx.z * sA;
    B += (size_t)blockIdx.z * sB;
    C += (size_t)blockIdx.z * sC;

    __shared__ float As[BK][LDT];   // A transposed: As[k][m]
    __shared__ float Bs[BK][LDT];   // Bs[k][n]

    const int t  = threadIdx.x;
    const int tx = t & 15;
    const int ty = t >> 4;
    const int m0 = blockIdx.y * BM;
    const int n0 = blockIdx.x * BN;

    // A-tile load mapping: 128 rows x 16 cols; 2 float4 per thread
    const int ar  = t >> 2;       // 0..63
    const int ac4 = t & 3;        // col group -> col ac4*4
    // B-tile load mapping: 16 rows x 128 cols; 2 float4 per thread
    const int br  = t >> 5;       // 0..7
    const int bc4 = t & 31;       // col group -> col bc4*4

    float acc[8][8];
    #pragma unroll
    for (int i = 0; i < 8; ++i)
        #pragma unroll
        for (int j = 0; j < 8; ++j) acc[i][j] = 0.f;

    for (int k0 = 0; k0 < Kd; k0 += BK) {
        float4 av0 = *(reinterpret_cast<const float4*>(A + (size_t)(m0 + ar)      * Kd + k0) + ac4);
        float4 av1 = *(reinterpret_cast<const float4*>(A + (size_t)(m0 + 64 + ar) * Kd + k0) + ac4);
        float4 bv0 = *(reinterpret_cast<const float4*>(B + (size_t)(k0 + br)      * N  + n0) + bc4);
        float4 bv1 = *(reinterpret_cast<const float4*>(B + (size_t)(k0 + 8 + br)  * N  + n0) + bc4);

        __syncthreads();  // previous iter's LDS reads done
        As[ac4*4+0][ar]      = av0.x;
        As[ac4*4+1][ar]      = av0.y;
        As[ac4*4+2][ar]      = av0.z;
        As[ac4*4+3][ar]      = av0.w;
        As[ac4*4+0][64+ar]   = av1.x;
        As[ac4*4+1][64+ar]   = av1.y;
        As[ac4*4+2][64+ar]   = av1.z;
        As[ac4*4+3][64+ar]   = av1.w;
        *reinterpret_cast<float4*>(&Bs[br][bc4*4])     = bv0;
        *reinterpret_cast<float4*>(&Bs[br+8][bc4*4])   = bv1;
        __syncthreads();

        #pragma unroll
        for (int kk = 0; kk < BK; ++kk) {
            float a[8], b[8];
            #pragma unroll
            for (int i = 0; i < 8; ++i) a[i] = As[kk][ty*8 + i];
            #pragma unroll
            for (int j = 0; j < 8; ++j) b[j] = Bs[kk][tx*8 + j];
            #pragma unroll
            for (int i = 0; i < 8; ++i)
                #pragma unroll
                for (int j = 0; j < 8; ++j)
                    acc[i][j] = fmaf(a[i], b[j], acc[i][j]);
        }
    }

    float bsv[8];
    if (bias) {
        float4 b0 = *reinterpret_cast<const float4*>(bias + n0 + tx*8);
        float4 b1 = *reinterpret_cast<const float4*>(bias + n0 + tx*8 + 4);
        bsv[0]=b0.x; bsv[1]=b0.y; bsv[2]=b0.z; bsv[3]=b0.w;
        bsv[4]=b1.x; bsv[5]=b1.y; bsv[6]=b1.z; bsv[7]=b1.w;
    } else {
        #pragma unroll
        for (int j = 0; j < 8; ++j) bsv[j] = 0.f;
    }

    #pragma unroll
    for (int i = 0; i < 8; ++i) {
        float* Cp = C + (size_t)(m0 + ty*8 + i) * N + n0 + tx*8;
        float4 o0, o1;
        o0.x = alpha*acc[i][0] + bsv[0];
        o0.y = alpha*acc[i][1] + bsv[1];
        o0.z = alpha*acc[i][2] + bsv[2];
        o0.w = alpha*acc[i][3] + bsv[3];
        o1.x = alpha*acc[i][4] + bsv[4];
        o1.y = alpha*acc[i][5] + bsv[5];
        o1.z = alpha*acc[i][6] + bsv[6];
        o1.w = alpha*acc[i][7] + bsv[7];
        *reinterpret_cast<float4*>(Cp)     = o0;
        *reinterpret_cast<float4*>(Cp + 4) = o1;
    }
}

// ---------------------------------------------------------------------------
// NT GEMM: C[m,n] = alpha * sum_d A[m,d]*B[n,d]   (both row-major, ld = Kd)
// Used for scores = Q @ K^T / sqrt(Dk). Batched via blockIdx.z.
// ---------------------------------------------------------------------------
__global__ __launch_bounds__(256)
void gemm_nt(const float* __restrict__ A, const float* __restrict__ B,
             float* __restrict__ C,
             int M, int N, int Kd, float alpha,
             size_t sA, size_t sB, size_t sC)
{
    A += (size_t)blockIdx.z * sA;
    B += (size_t)blockIdx.z * sB;
    C += (size_t)blockIdx.z * sC;

    __shared__ float As[BK][LDT];   // As[d][m]
    __shared__ float Bs[BK][LDT];   // Bs[d][n]

    const int t  = threadIdx.x;
    const int tx = t & 15;
    const int ty = t >> 4;
    const int m0 = blockIdx.y * BM;
    const int n0 = blockIdx.x * BN;

    const int ar  = t >> 2;   // 0..63
    const int ac4 = t & 3;

    float acc[8][8];
    #pragma unroll
    for (int i = 0; i < 8; ++i)
        #pragma unroll
        for (int j = 0; j < 8; ++j) acc[i][j] = 0.f;

    for (int k0 = 0; k0 < Kd; k0 += BK) {
        float4 av0 = *(reinterpret_cast<const float4*>(A + (size_t)(m0 + ar)      * Kd + k0) + ac4);
        float4 av1 = *(reinterpret_cast<const float4*>(A + (size_t)(m0 + 64 + ar) * Kd + k0) + ac4);
        float4 bv0 = *(reinterpret_cast<const float4*>(B + (size_t)(n0 + ar)      * Kd + k0) + ac4);
        float4 bv1 = *(reinterpret_cast<const float4*>(B + (size_t)(n0 + 64 + ar) * Kd + k0) + ac4);

        __syncthreads();
        As[ac4*4+0][ar]    = av0.x;
        As[ac4*4+1][ar]    = av0.y;
        As[ac4*4+2][ar]    = av0.z;
        As[ac4*4+3][ar]    = av0.w;
        As[ac4*4+0][64+ar] = av1.x;
        As[ac4*4+1][64+ar] = av1.y;
        As[ac4*4+2][64+ar] = av1.z;
        As[ac4*4+3][64+ar] = av1.w;
        Bs[ac4*4+0][ar]    = bv0.x;
        Bs[ac4*4+1][ar]    = bv0.y;
        Bs[ac4*4+2][ar]    = bv0.z;
        Bs[ac4*4+3][ar]    = bv0.w;
        Bs[ac4*4+0][64+ar] = bv1.x;
        Bs[ac4*4+1][64+ar] = bv1.y;
        Bs[ac4*4+2][64+ar] = bv1.z;
        Bs[ac4*4+3][64+ar] = bv1.w;
        __syncthreads();

        #pragma unroll
        for (int kk = 0; kk < BK; ++kk) {
            float a[8], b[8];
            #pragma unroll
            for (int i = 0; i < 8; ++i) a[i] = As[kk][ty*8 + i];
            #pragma unroll
            for (int j = 0; j < 8; ++j) b[j] = Bs[kk][tx*8 + j];
            #pragma unroll
            for (int i = 0; i < 8; ++i)
                #pragma unroll
                for (int j = 0; j < 8; ++j)
                    acc[i][j] = fmaf(a[i], b[j], acc[i][j]);
        }
    }

    #pragma unroll
    for (int i = 0; i < 8; ++i) {
        float* Cp = C + (size_t)(m0 + ty*8 + i) * N + n0 + tx*8;
        float4 o0, o1;
        o0.x = alpha*acc[i][0]; o0.y = alpha*acc[i][1];
        o0.z = alpha*acc[i][2]; o0.w = alpha*acc[i][3];
        o1.x = alpha*acc[i][4]; o1.y = alpha*acc[i][5];
        o1.z = alpha*acc[i][6]; o1.w = alpha*acc[i][7];
        *reinterpret_cast<float4*>(Cp)     = o0;
        *reinterpret_cast<float4*>(Cp + 4) = o1;
    }
}

// ---------------------------------------------------------------------------
// Column-softmax stats (softmax over the ROW index q, per column k).
// Partial pass: each block owns 256 columns x rows_per rows (online m/Z).
// ---------------------------------------------------------------------------
__global__ __launch_bounds__(256)
void colstats_partial(const float* __restrict__ S, float* __restrict__ mP,
                      float* __restrict__ ZP, int rows_total, int cols, int rows_per)
{
    const int b = blockIdx.z;
    const int c = blockIdx.x * 256 + threadIdx.x;
    const int r0 = blockIdx.y * rows_per;
    const float* Sp = S + ((size_t)b * rows_total + r0) * cols + c;

    float m = -INFINITY, Z = 0.f;
    for (int q = 0; q < rows_per; ++q) {
        float s = Sp[(size_t)q * cols];
        float nm = fmaxf(m, s);
        Z = Z * __expf(m - nm) + __expf(s - nm);
        m = nm;
    }
    size_t o = ((size_t)b * gridDim.y + blockIdx.y) * cols + c;
    mP[o] = m;
    ZP[o] = Z;
}

__global__ __launch_bounds__(256)
void colstats_combine(const float* __restrict__ mP, const float* __restrict__ ZP,
                      float* __restrict__ mOut, float* __restrict__ rZ,
                      int cols, int chunks)
{
    const int b = blockIdx.y;
    const int c = blockIdx.x * 256 + threadIdx.x;
    float m = -INFINITY, Z = 0.f;
    for (int ch = 0; ch < chunks; ++ch) {
        size_t o = ((size_t)b * chunks + ch) * cols + c;
        float mi = mP[o];
        float Zi = ZP[o];
        float nm = fmaxf(m, mi);
        Z = Z * __expf(m - nm) + Zi * __expf(mi - nm);
        m = nm;
    }
    mOut[(size_t)b * cols + c] = m;
    rZ[(size_t)b * cols + c]   = 1.0f / Z;
}

// ---------------------------------------------------------------------------
// In-place normalize: P[q,k] = exp(S[q,k] - m[k]) * rZ[k]
// ---------------------------------------------------------------------------
__global__ __launch_bounds__(256)
void normalize_cols(float* __restrict__ S, const float* __restrict__ mIn,
                    const float* __restrict__ rZ, size_t total, int cols, int rowscols)
{
    size_t i4 = (size_t)blockIdx.x * 256 + threadIdx.x;
    size_t base = i4 * 4;
    if (base >= total) return;
    int b   = (int)(base / (size_t)rowscols);
    int col = (int)(base % (size_t)cols);
    float4 s  = *reinterpret_cast<float4*>(S + base);
    float4 mv = *reinterpret_cast<const float4*>(mIn + (size_t)b * cols + col);
    float4 zv = *reinterpret_cast<const float4*>(rZ  + (size_t)b * cols + col);
    s.x = __expf(s.x - mv.x) * zv.x;
    s.y = __expf(s.y - mv.y) * zv.y;
    s.z = __expf(s.z - mv.z) * zv.z;
    s.w = __expf(s.w - mv.w) * zv.w;
    *reinterpret_cast<float4*>(S + base) = s;
}

// ---------------------------------------------------------------------------
extern "C" void kernel_launch(void* const* d_in, const int* in_sizes, int n_in,
                              void* d_out, int out_size, void* d_ws, size_t ws_size,
                              hipStream_t stream)
{
    const float* x  = (const float*)d_in[0];
    const float* Wq = (const float*)d_in[1];
    const float* bq = (const float*)d_in[2];
    const float* Wk = (const float*)d_in[3];
    const float* bk = (const float*)d_in[4];
    const float* Wv = (const float*)d_in[5];
    const float* bv = (const float*)d_in[6];
    float* out = (float*)d_out;

    const int B = BATCH, S = SEQ, E = EMB, D = DK;
    const size_t MT = (size_t)B * S;            // 8192 rows total

    // Workspace layout (floats)
    float* ws = (float*)d_ws;
    float* Q   = ws;                            // MT*D
    float* Km  = Q  + MT * D;                   // MT*D
    float* V   = Km + MT * D;                   // MT*D
    float* Sc  = V  + MT * D;                   // B*S*S
    float* mC  = Sc + (size_t)B * S * S;        // B*S
    float* rZ  = mC + (size_t)B * S;            // B*S
    float* mP  = rZ + (size_t)B * S;            // B*8*S
    float* ZP  = mP + (size_t)B * 8 * S;        // B*8*S

    dim3 blk(256);

    // 1) Projections: Q/K/V = x @ W + b   (M=8192, N=1024, K=1024)
    dim3 g1(D / BN, MT / BM, 1);
    gemm_nn<<<g1, blk, 0, stream>>>(x, Wq, bq, Q,  (int)MT, D, E, 1.f, 0, 0, 0);
    gemm_nn<<<g1, blk, 0, stream>>>(x, Wk, bk, Km, (int)MT, D, E, 1.f, 0, 0, 0);
    gemm_nn<<<g1, blk, 0, stream>>>(x, Wv, bv, V,  (int)MT, D, E, 1.f, 0, 0, 0);

    // 2) Scores: S_b = Q_b @ K_b^T / 32   (per batch, M=N=2048, K=1024)
    dim3 g2(S / BN, S / BM, B);
    gemm_nt<<<g2, blk, 0, stream>>>(Q, Km, Sc, S, S, D, 0.03125f,
                                    (size_t)S * D, (size_t)S * D, (size_t)S * S);

    // 3) Column-softmax stats (softmax over q axis => per-column over rows)
    dim3 g3(S / 256, 8, B);
    colstats_partial<<<g3, blk, 0, stream>>>(Sc, mP, ZP, S, S, S / 8);
    dim3 g4(S / 256, B);
    colstats_combine<<<g4, blk, 0, stream>>>(mP, ZP, mC, rZ, S, 8);

    // 4) Normalize in place: P = exp(S - m_col) * rZ_col
    size_t total = (size_t)B * S * S;
    dim3 g5((unsigned)((total / 4 + 255) / 256));
    normalize_cols<<<g5, blk, 0, stream>>>(Sc, mC, rZ, total, S, S * S);

    // 5) Output: out_b = P_b @ V_b   (per batch, M=2048, N=1024, K=2048)
    dim3 g6(D / BN, S / BM, B);
    gemm_nn<<<g6, blk, 0, stream>>>(Sc, V, nullptr, out, S, D, S, 1.f,
                                    (size_t)S * S, (size_t)S * D, (size_t)S * D);
}

// Round 2
// 611.437 us; speedup vs baseline: 2.6227x; 2.6227x over previous
//
#include <hip/hip_runtime.h>
#include <math.h>

typedef unsigned short ushort_t;
typedef __attribute__((ext_vector_type(8))) short short8;
typedef __attribute__((ext_vector_type(4))) float floatx4;

#define BATCH 4
#define SEQ   2048
#define EMB   1024

// MFMA GEMM tile
#define GBM 128
#define GBN 128
#define GBK 32
#define LDSK 40   // padded LDS k-stride in bf16 elems (80 B rows -> 2-way bank alias, free)

// ---------------------------------------------------------------------------
// bf16 split helpers (RNE)
// ---------------------------------------------------------------------------
__device__ __forceinline__ ushort_t f2bf(float f) {
    unsigned u = __float_as_uint(f);
    u += 0x7fff + ((u >> 16) & 1);
    return (ushort_t)(u >> 16);
}
__device__ __forceinline__ float bf2f(ushort_t h) {
    return __uint_as_float(((unsigned)h) << 16);
}

// ---------------------------------------------------------------------------
// Elementwise split: fp32 -> (hi, lo) bf16 arrays. n4 = count/4.
// ---------------------------------------------------------------------------
__global__ __launch_bounds__(256)
void split_elem(const float* __restrict__ in, ushort_t* __restrict__ hi,
                ushort_t* __restrict__ lo, size_t n4)
{
    size_t i = (size_t)blockIdx.x * 256 + threadIdx.x;
    if (i >= n4) return;
    float4 v = reinterpret_cast<const float4*>(in)[i];
    float vv[4] = {v.x, v.y, v.z, v.w};
    unsigned h[4], l[4];
    #pragma unroll
    for (int j = 0; j < 4; ++j) {
        h[j] = f2bf(vv[j]);
        l[j] = f2bf(vv[j] - bf2f((ushort_t)h[j]));
    }
    uint2 hv, lv;
    hv.x = h[0] | (h[1] << 16); hv.y = h[2] | (h[3] << 16);
    lv.x = l[0] | (l[1] << 16); lv.y = l[2] | (l[3] << 16);
    *reinterpret_cast<uint2*>(hi + i * 4) = hv;
    *reinterpret_cast<uint2*>(lo + i * 4) = lv;
}

// ---------------------------------------------------------------------------
// Split + transpose: W [rows][cols] fp32 -> T [cols][rows] bf16 hi/lo.
// ---------------------------------------------------------------------------
__global__ __launch_bounds__(256)
void split_transpose(const float* __restrict__ W, ushort_t* __restrict__ Thi,
                     ushort_t* __restrict__ Tlo, int rows, int cols)
{
    __shared__ float tile[32][33];
    const int r0 = blockIdx.y * 32, c0 = blockIdx.x * 32;
    const int tr = threadIdx.x >> 5;   // 0..7
    const int tc = threadIdx.x & 31;
    #pragma unroll
    for (int rr = 0; rr < 32; rr += 8)
        tile[tr + rr][tc] = W[(size_t)(r0 + tr + rr) * cols + c0 + tc];
    __syncthreads();
    #pragma unroll
    for (int rr = 0; rr < 32; rr += 8) {
        float v = tile[tc][tr + rr];
        size_t o = (size_t)(c0 + tr + rr) * rows + r0 + tc;
        ushort_t h = f2bf(v);
        Thi[o] = h;
        Tlo[o] = f2bf(v - bf2f(h));
    }
}

// ---------------------------------------------------------------------------
// NT MFMA GEMM on split-bf16 pairs:
//   C[m][n] = alpha * sum_k A[m][k]*B[n][k]  (+ bias)
// A = Ahi+Alo, B = Bhi+Blo (fp32 emulation: hh + hl + lh).
// BIAS_MODE: 0 none, 1 per-n (bias[col]), 2 per-m (bias[row])
// STORE_SPLIT: 0 -> fp32 to C; 1 -> split bf16 to Chi/Clo
// Batched via blockIdx.z with element strides bsA/bsB/bsC.
// ---------------------------------------------------------------------------
template<int BIAS_MODE, int STORE_SPLIT>
__global__ __launch_bounds__(256)
void gemm_bf16pair(const ushort_t* __restrict__ Ahi, const ushort_t* __restrict__ Alo,
                   int ldA, size_t bsA,
                   const ushort_t* __restrict__ Bhi, const ushort_t* __restrict__ Blo,
                   int ldB, size_t bsB,
                   float* __restrict__ C, ushort_t* __restrict__ Chi, ushort_t* __restrict__ Clo,
                   int ldC, size_t bsC,
                   int K, float alpha, const float* __restrict__ bias)
{
    const size_t zA = (size_t)blockIdx.z * bsA;
    const size_t zB = (size_t)blockIdx.z * bsB;
    const size_t zC = (size_t)blockIdx.z * bsC;

    __shared__ alignas(16) ushort_t As[2][GBM][LDSK];   // [hi/lo][m][k]
    __shared__ alignas(16) ushort_t Bs[2][GBN][LDSK];   // [hi/lo][n][k]

    const int t  = threadIdx.x;
    const int m0 = blockIdx.y * GBM;
    const int n0 = blockIdx.x * GBN;

    // staging: chunk c covers (row=c>>2, k=(c&3)*8 .. +7); thread owns c=t and c=t+256
    const int sr = t >> 2;          // 0..63
    const int sk = (t & 3) * 8;

    const int lane = t & 63;
    const int wid  = t >> 6;        // wave 0..3
    const int wm = (wid & 1) * 64;
    const int wn = (wid >> 1) * 64;
    const int fr = lane & 15;       // fragment row (m or n)
    const int fq = lane >> 4;       // k-quad: k = fq*8 + j

    floatx4 acc[4][4];
    #pragma unroll
    for (int i = 0; i < 4; ++i)
        #pragma unroll
        for (int j = 0; j < 4; ++j)
            #pragma unroll
            for (int r = 0; r < 4; ++r) acc[i][j][r] = 0.f;

    for (int k0 = 0; k0 < K; k0 += GBK) {
        const size_t aoff = zA + (size_t)(m0 + sr) * ldA + k0 + sk;
        const size_t boff = zB + (size_t)(n0 + sr) * ldB + k0 + sk;
        const size_t astep = (size_t)64 * ldA;
        const size_t bstep = (size_t)64 * ldB;
        int4 a0 = *reinterpret_cast<const int4*>(Ahi + aoff);
        int4 a1 = *reinterpret_cast<const int4*>(Ahi + aoff + astep);
        int4 a2 = *reinterpret_cast<const int4*>(Alo + aoff);
        int4 a3 = *reinterpret_cast<const int4*>(Alo + aoff + astep);
        int4 b0 = *reinterpret_cast<const int4*>(Bhi + boff);
        int4 b1 = *reinterpret_cast<const int4*>(Bhi + boff + bstep);
        int4 b2 = *reinterpret_cast<const int4*>(Blo + boff);
        int4 b3 = *reinterpret_cast<const int4*>(Blo + boff + bstep);

        __syncthreads();   // prior iter's LDS reads complete
        *reinterpret_cast<int4*>(&As[0][sr     ][sk]) = a0;
        *reinterpret_cast<int4*>(&As[0][sr + 64][sk]) = a1;
        *reinterpret_cast<int4*>(&As[1][sr     ][sk]) = a2;
        *reinterpret_cast<int4*>(&As[1][sr + 64][sk]) = a3;
        *reinterpret_cast<int4*>(&Bs[0][sr     ][sk]) = b0;
        *reinterpret_cast<int4*>(&Bs[0][sr + 64][sk]) = b1;
        *reinterpret_cast<int4*>(&Bs[1][sr     ][sk]) = b2;
        *reinterpret_cast<int4*>(&Bs[1][sr + 64][sk]) = b3;
        __syncthreads();

        short8 ah[4], al[4];
        #pragma unroll
        for (int i = 0; i < 4; ++i) {
            ah[i] = *reinterpret_cast<const short8*>(&As[0][wm + i*16 + fr][fq*8]);
            al[i] = *reinterpret_cast<const short8*>(&As[1][wm + i*16 + fr][fq*8]);
        }
        #pragma unroll
        for (int j = 0; j < 4; ++j) {
            short8 bh = *reinterpret_cast<const short8*>(&Bs[0][wn + j*16 + fr][fq*8]);
            short8 bl = *reinterpret_cast<const short8*>(&Bs[1][wn + j*16 + fr][fq*8]);
            #pragma unroll
            for (int i = 0; i < 4; ++i) {
                acc[i][j] = __builtin_amdgcn_mfma_f32_16x16x32_bf16(ah[i], bh, acc[i][j], 0, 0, 0);
                acc[i][j] = __builtin_amdgcn_mfma_f32_16x16x32_bf16(ah[i], bl, acc[i][j], 0, 0, 0);
                acc[i][j] = __builtin_amdgcn_mfma_f32_16x16x32_bf16(al[i], bh, acc[i][j], 0, 0, 0);
            }
        }
    }

    // Epilogue. C/D layout: col = lane&15, row = (lane>>4)*4 + r  [m89-verified]
    #pragma unroll
    for (int i = 0; i < 4; ++i) {
        #pragma unroll
        for (int j = 0; j < 4; ++j) {
            const int col = n0 + wn + j*16 + fr;
            float bn = 0.f;
            if (BIAS_MODE == 1) bn = bias[col];
            #pragma unroll
            for (int r = 0; r < 4; ++r) {
                const int row = m0 + wm + i*16 + fq*4 + r;
                float v = acc[i][j][r] * alpha + bn;
                if (BIAS_MODE == 2) v += bias[row];
                const size_t o = zC + (size_t)row * ldC + col;
                if (STORE_SPLIT) {
                    ushort_t h = f2bf(v);
                    Chi[o] = h;
                    Clo[o] = f2bf(v - bf2f(h));
                } else {
                    C[o] = v;
                }
            }
        }
    }
}

// ---------------------------------------------------------------------------
// Column-softmax (softmax over the QUERY axis => per-column over rows).
// ---------------------------------------------------------------------------
__global__ __launch_bounds__(256)
void colstats_partial(const float* __restrict__ S, float* __restrict__ mP,
                      float* __restrict__ ZP, int rows_total, int cols, int rows_per)
{
    const int b = blockIdx.z;
    const int c = blockIdx.x * 256 + threadIdx.x;
    const int r0 = blockIdx.y * rows_per;
    const float* Sp = S + ((size_t)b * rows_total + r0) * cols + c;

    float m = -INFINITY, Z = 0.f;
    for (int q = 0; q < rows_per; ++q) {
        float s = Sp[(size_t)q * cols];
        float nm = fmaxf(m, s);
        Z = Z * __expf(m - nm) + __expf(s - nm);
        m = nm;
    }
    size_t o = ((size_t)b * gridDim.y + blockIdx.y) * cols + c;
    mP[o] = m;
    ZP[o] = Z;
}

__global__ __launch_bounds__(256)
void colstats_combine(const float* __restrict__ mP, const float* __restrict__ ZP,
                      float* __restrict__ mOut, float* __restrict__ rZ,
                      int cols, int chunks)
{
    const int b = blockIdx.y;
    const int c = blockIdx.x * 256 + threadIdx.x;
    float m = -INFINITY, Z = 0.f;
    for (int ch = 0; ch < chunks; ++ch) {
        size_t o = ((size_t)b * chunks + ch) * cols + c;
        float mi = mP[o], Zi = ZP[o];
        float nm = fmaxf(m, mi);
        Z = Z * __expf(m - nm) + Zi * __expf(mi - nm);
        m = nm;
    }
    mOut[(size_t)b * cols + c] = m;
    rZ[(size_t)b * cols + c]   = 1.0f / Z;
}

// ---------------------------------------------------------------------------
// Normalize + split: P = exp(S - m_col) * rZ_col -> bf16 hi/lo pair.
// ---------------------------------------------------------------------------
__global__ __launch_bounds__(256)
void normalize_split(const float* __restrict__ S, const float* __restrict__ mIn,
                     const float* __restrict__ rZ, ushort_t* __restrict__ Phi,
                     ushort_t* __restrict__ Plo, size_t total4, int cols, int rowscols)
{
    size_t i4 = (size_t)blockIdx.x * 256 + threadIdx.x;
    if (i4 >= total4) return;
    size_t base = i4 * 4;
    int b   = (int)(base / (size_t)rowscols);
    int col = (int)(base % (size_t)cols);
    float4 s = *reinterpret_cast<const float4*>(S + base);
    const float* mv = mIn + (size_t)b * cols + col;
    const float* zv = rZ  + (size_t)b * cols + col;
    float p[4];
    p[0] = __expf(s.x - mv[0]) * zv[0];
    p[1] = __expf(s.y - mv[1]) * zv[1];
    p[2] = __expf(s.z - mv[2]) * zv[2];
    p[3] = __expf(s.w - mv[3]) * zv[3];
    unsigned h[4], l[4];
    #pragma unroll
    for (int j = 0; j < 4; ++j) {
        h[j] = f2bf(p[j]);
        l[j] = f2bf(p[j] - bf2f((ushort_t)h[j]));
    }
    uint2 hv, lv;
    hv.x = h[0] | (h[1] << 16); hv.y = h[2] | (h[3] << 16);
    lv.x = l[0] | (l[1] << 16); lv.y = l[2] | (l[3] << 16);
    *reinterpret_cast<uint2*>(Phi + base) = hv;
    *reinterpret_cast<uint2*>(Plo + base) = lv;
}

// ---------------------------------------------------------------------------
extern "C" void kernel_launch(void* const* d_in, const int* in_sizes, int n_in,
                              void* d_out, int out_size, void* d_ws, size_t ws_size,
                              hipStream_t stream)
{
    const float* x  = (const float*)d_in[0];
    const float* Wq = (const float*)d_in[1];
    const float* bq = (const float*)d_in[2];
    const float* Wk = (const float*)d_in[3];
    const float* bk = (const float*)d_in[4];
    const float* Wv = (const float*)d_in[5];
    const float* bv = (const float*)d_in[6];

    const int S = SEQ, E = EMB;
    const size_t MT = (size_t)BATCH * S;      // 8192
    const size_t MB = 1024 * 1024;

    // Workspace layout (overlays are safe: stream-ordered, lifetimes disjoint):
    //   [0,64)    Sc fp32         (live: scores..normalize)
    //   [0,16)    xhi | [16,32) xlo          (live: split..projections)
    //   [32,44)   Wt hi/lo x3                (live: transpose..projections)
    //   [64,96)   Qhi/Qlo  -> later Phi/...  (Q dead after scores)
    //   [96,128)  Khi/Klo  -> later ...Plo
    //   [128,160) Vthi/Vtlo
    //   [160,161) softmax stats
    char* base = (char*)d_ws;
    float*    Sc   = (float*)base;
    ushort_t* xhi  = (ushort_t*)base;
    ushort_t* xlo  = (ushort_t*)(base + 16 * MB);
    ushort_t* Wqth = (ushort_t*)(base + 32 * MB);
    ushort_t* Wqtl = (ushort_t*)(base + 34 * MB);
    ushort_t* Wkth = (ushort_t*)(base + 36 * MB);
    ushort_t* Wktl = (ushort_t*)(base + 38 * MB);
    ushort_t* Wvth = (ushort_t*)(base + 40 * MB);
    ushort_t* Wvtl = (ushort_t*)(base + 42 * MB);
    ushort_t* Qhi  = (ushort_t*)(base + 64 * MB);
    ushort_t* Qlo  = (ushort_t*)(base + 80 * MB);
    ushort_t* Khi  = (ushort_t*)(base + 96 * MB);
    ushort_t* Klo  = (ushort_t*)(base + 112 * MB);
    ushort_t* Phi  = (ushort_t*)(base + 64 * MB);   // overlays Q (dead)
    ushort_t* Plo  = (ushort_t*)(base + 96 * MB);   // overlays K (dead)
    ushort_t* Vth  = (ushort_t*)(base + 128 * MB);
    ushort_t* Vtl  = (ushort_t*)(base + 144 * MB);
    float* mC = (float*)(base + 160 * MB);
    float* rZ = mC + (size_t)BATCH * S;
    float* mP = rZ + (size_t)BATCH * S;
    float* ZP = mP + (size_t)BATCH * 8 * S;

    dim3 blk(256);

    // 1) Split x into bf16 hi/lo
    split_elem<<<8192, blk, 0, stream>>>(x, xhi, xlo, MT * E / 4);

    // 2) Split+transpose weights: Wt [n][e]
    dim3 gt(E / 32, E / 32);
    split_transpose<<<gt, blk, 0, stream>>>(Wq, Wqth, Wqtl, E, E);
    split_transpose<<<gt, blk, 0, stream>>>(Wk, Wkth, Wktl, E, E);
    split_transpose<<<gt, blk, 0, stream>>>(Wv, Wvth, Wvtl, E, E);

    // 3) Projections (NT): Q/K = x . Wt^T + b, split-stored
    dim3 gq(E / GBN, MT / GBM, 1);   // (8, 64)
    gemm_bf16pair<1, 1><<<gq, blk, 0, stream>>>(xhi, xlo, E, 0, Wqth, Wqtl, E, 0,
        nullptr, Qhi, Qlo, E, 0, E, 1.f, bq);
    gemm_bf16pair<1, 1><<<gq, blk, 0, stream>>>(xhi, xlo, E, 0, Wkth, Wktl, E, 0,
        nullptr, Khi, Klo, E, 0, E, 1.f, bk);
    // Vt[d][key] = Wvt . x^T + bv (per-row bias), split-stored, ldC = MT
    dim3 gv(MT / GBN, E / GBM, 1);   // (64, 8)
    gemm_bf16pair<2, 1><<<gv, blk, 0, stream>>>(Wvth, Wvtl, E, 0, xhi, xlo, E, 0,
        nullptr, Vth, Vtl, (int)MT, 0, E, 1.f, bv);

    // 4) Scores (NT, batched): Sc_b = Q_b . K_b^T / 32, fp32
    dim3 gs(S / GBN, S / GBM, BATCH);   // (16,16,4)
    gemm_bf16pair<0, 0><<<gs, blk, 0, stream>>>(Qhi, Qlo, E, (size_t)S * E,
        Khi, Klo, E, (size_t)S * E,
        Sc, nullptr, nullptr, S, (size_t)S * S, E, 0.03125f, nullptr);

    // 5) Column softmax stats
    dim3 g3(S / 256, 8, BATCH);
    colstats_partial<<<g3, blk, 0, stream>>>(Sc, mP, ZP, S, S, S / 8);
    dim3 g4(S / 256, BATCH);
    colstats_combine<<<g4, blk, 0, stream>>>(mP, ZP, mC, rZ, S, 8);

    // 6) Normalize + split P
    size_t total4 = (size_t)BATCH * S * S / 4;
    normalize_split<<<(unsigned)((total4 + 255) / 256), blk, 0, stream>>>(
        Sc, mC, rZ, Phi, Plo, total4, S, S * S);

    // 7) Output (NT, batched): out_b = P_b . Vt^T (Vt batch via column offset)
    dim3 go(E / GBN, S / GBM, BATCH);   // (8,16,4)
    gemm_bf16pair<0, 0><<<go, blk, 0, stream>>>(Phi, Plo, S, (size_t)S * S,
        Vth, Vtl, (int)MT, (size_t)S,
        (float*)d_out, nullptr, nullptr, E, (size_t)S * E, S, 1.f, nullptr);
}